// Round 1
// baseline (385.670 us; speedup 1.0000x reference)
//
#include <hip/hip_runtime.h>
#include <math.h>

#define BN 4096
#define SZ 2048
#define HIDN 128
#define NT 8

// ws layout (bytes):
//   [0, 16384)       idx  int[4096]   bucketed sample indices (grouped by task)
//   [16384, ...)     meta int[]: [0..8]=cnt (bucket 8 = invalid), [16..25]=offs,
//                    [32..40]=cursor, [48]=int64-flag
//   [16640, +2MB)    H float[4096*128]

__global__ void k_init(const int* __restrict__ task, int* __restrict__ meta) {
    int tid = threadIdx.x;
    if (tid < 9) meta[tid] = 0;
    if (tid < 9) meta[32 + tid] = 0;
    // Detect int64 task_id: odd 32-bit words would all be 0 or -1 (sign ext).
    bool ok = true;
    int v = task[2 * tid + 1];
    ok = (v == 0 || v == -1);
    unsigned long long m = __ballot(ok);
    if (tid == 0) meta[48] = (m == ~0ull) ? 1 : 0;
}

__device__ inline int bucket_of(const int* task, int b, int f64) {
    int t = f64 ? task[2 * b] : task[b];
    return (t < 0) ? 8 : (t > 7 ? 7 : t);
}

__global__ void k_hist(const int* __restrict__ task, int* __restrict__ meta) {
    int b = blockIdx.x * 256 + threadIdx.x;
    if (b >= BN) return;
    int f = meta[48];
    atomicAdd(&meta[bucket_of(task, b, f)], 1);
}

__global__ void k_scan(int* __restrict__ meta) {
    int s = 0;
    for (int i = 0; i < 9; i++) { meta[16 + i] = s; meta[32 + i] = s; s += meta[i]; }
    meta[16 + 9] = s;
}

__global__ void k_scatter(const int* __restrict__ task, int* __restrict__ meta,
                          int* __restrict__ idxb) {
    int b = blockIdx.x * 256 + threadIdx.x;
    if (b >= BN) return;
    int f = meta[48];
    int p = atomicAdd(&meta[32 + bucket_of(task, b, f)], 1);
    idxb[p] = b;
}

// GEMM1: H[r, h] = silu( sum_k x[g(r), k] * Wd[t, k, h] + bd[t, h] )
// grid = NT * 256 tiles of 16 rows, block 256 (h = tid&127, sg = tid>>7 -> 8 rows each)
__global__ __launch_bounds__(256) void k_gemm1(
    const float* __restrict__ x, const float* __restrict__ Wd,
    const float* __restrict__ bd, const int* __restrict__ idxb,
    const int* __restrict__ meta, float* __restrict__ H) {
    int t = blockIdx.x >> 8;
    int tile = blockIdx.x & 255;
    int n = meta[t];
    int r0 = tile * 16;
    if (r0 >= n) return;
    int base = meta[16 + t];

    __shared__ float XL[16][32];
    __shared__ int gidx[16];
    int tid = threadIdx.x;
    if (tid < 16) {
        int r = r0 + tid;
        gidx[tid] = idxb[base + (r < n ? r : n - 1)];
    }
    __syncthreads();

    int h = tid & 127;
    int sg = tid >> 7;  // 0..1 -> rows sg*8 .. sg*8+7
    const float* wd = Wd + (size_t)t * SZ * HIDN + h;

    float acc[8];
#pragma unroll
    for (int i = 0; i < 8; i++) acc[i] = 0.f;

    for (int k0 = 0; k0 < SZ; k0 += 32) {
        // stage 16 rows x 32 k of x
        {
            int kk = tid & 31, s = tid >> 5;  // s = 0..7
            XL[s][kk]     = x[(size_t)gidx[s] * SZ + k0 + kk];
            XL[s + 8][kk] = x[(size_t)gidx[s + 8] * SZ + k0 + kk];
        }
        __syncthreads();
#pragma unroll
        for (int kk4 = 0; kk4 < 8; kk4++) {
            float w0 = wd[(size_t)(k0 + kk4 * 4 + 0) * HIDN];
            float w1 = wd[(size_t)(k0 + kk4 * 4 + 1) * HIDN];
            float w2 = wd[(size_t)(k0 + kk4 * 4 + 2) * HIDN];
            float w3 = wd[(size_t)(k0 + kk4 * 4 + 3) * HIDN];
#pragma unroll
            for (int s = 0; s < 8; s++) {
                float4 xv = *reinterpret_cast<const float4*>(&XL[sg * 8 + s][kk4 * 4]);
                acc[s] = fmaf(xv.x, w0, acc[s]);
                acc[s] = fmaf(xv.y, w1, acc[s]);
                acc[s] = fmaf(xv.z, w2, acc[s]);
                acc[s] = fmaf(xv.w, w3, acc[s]);
            }
        }
        __syncthreads();
    }

    float bias = bd[t * HIDN + h];
#pragma unroll
    for (int s = 0; s < 8; s++) {
        int r = r0 + sg * 8 + s;
        if (r < n) {
            float v = acc[s] + bias;
            float sv = v / (1.f + __expf(-v));
            H[(size_t)(base + r) * HIDN + h] = sv;
        }
    }
}

// GEMM2: out[g(r), c] = x[g(r), c] + sum_h H[r, h] * Wu[t, h, c] + bu[t, c]
// grid = NT * 256 * 4 (16-row tile x 512-col chunk), block 256 (2 cols/thread)
__global__ __launch_bounds__(256) void k_gemm2(
    const float* __restrict__ x, const float* __restrict__ Wu,
    const float* __restrict__ bu, const int* __restrict__ idxb,
    const int* __restrict__ meta, const float* __restrict__ H,
    float* __restrict__ out) {
    int bid = blockIdx.x;
    int t = bid >> 10;
    int tile = (bid >> 2) & 255;
    int cchunk = bid & 3;
    int n = meta[t];
    int r0 = tile * 16;
    if (r0 >= n) return;
    int base = meta[16 + t];

    __shared__ float HL[16][HIDN];
    __shared__ int gidx[16];
    int tid = threadIdx.x;
    if (tid < 16) {
        int r = r0 + tid;
        gidx[tid] = idxb[base + (r < n ? r : n - 1)];
    }
    {
        int hh = tid & 127, s2 = tid >> 7;
#pragma unroll
        for (int p = 0; p < 8; p++) {
            int s = p * 2 + s2;
            int r = r0 + s;
            HL[s][hh] = H[(size_t)(base + (r < n ? r : 0)) * HIDN + hh];
        }
    }
    __syncthreads();

    int c = cchunk * 512 + tid;  // this thread handles cols c and c+256
    const float* wu = Wu + (size_t)t * HIDN * SZ;

    float acc0[16], acc1[16];
#pragma unroll
    for (int s = 0; s < 16; s++) { acc0[s] = 0.f; acc1[s] = 0.f; }

    for (int h4 = 0; h4 < HIDN / 4; h4++) {
        float w00 = wu[(size_t)(h4 * 4 + 0) * SZ + c];
        float w01 = wu[(size_t)(h4 * 4 + 1) * SZ + c];
        float w02 = wu[(size_t)(h4 * 4 + 2) * SZ + c];
        float w03 = wu[(size_t)(h4 * 4 + 3) * SZ + c];
        float w10 = wu[(size_t)(h4 * 4 + 0) * SZ + c + 256];
        float w11 = wu[(size_t)(h4 * 4 + 1) * SZ + c + 256];
        float w12 = wu[(size_t)(h4 * 4 + 2) * SZ + c + 256];
        float w13 = wu[(size_t)(h4 * 4 + 3) * SZ + c + 256];
#pragma unroll
        for (int s = 0; s < 16; s++) {
            float4 hv = *reinterpret_cast<const float4*>(&HL[s][h4 * 4]);
            acc0[s] = fmaf(hv.x, w00, acc0[s]);
            acc0[s] = fmaf(hv.y, w01, acc0[s]);
            acc0[s] = fmaf(hv.z, w02, acc0[s]);
            acc0[s] = fmaf(hv.w, w03, acc0[s]);
            acc1[s] = fmaf(hv.x, w10, acc1[s]);
            acc1[s] = fmaf(hv.y, w11, acc1[s]);
            acc1[s] = fmaf(hv.z, w12, acc1[s]);
            acc1[s] = fmaf(hv.w, w13, acc1[s]);
        }
    }

    float b0 = bu[t * SZ + c];
    float b1 = bu[t * SZ + c + 256];
#pragma unroll
    for (int s = 0; s < 16; s++) {
        int r = r0 + s;
        if (r < n) {
            size_t g = (size_t)gidx[s] * SZ;
            out[g + c]       = x[g + c] + acc0[s] + b0;
            out[g + c + 256] = x[g + c + 256] + acc1[s] + b1;
        }
    }
}

// Passthrough for invalid task ids (bucket 8): out = x
__global__ void k_pass(const float* __restrict__ x, const int* __restrict__ idxb,
                       const int* __restrict__ meta, float* __restrict__ out) {
    int n8 = meta[8];
    if (n8 == 0) return;
    long total = (long)n8 * SZ;
    int base8 = meta[16 + 8];
    for (long i = (long)blockIdx.x * blockDim.x + threadIdx.x; i < total;
         i += (long)gridDim.x * blockDim.x) {
        int r = (int)(i >> 11);
        int cc = (int)(i & (SZ - 1));
        int g = idxb[base8 + r];
        out[(size_t)g * SZ + cc] = x[(size_t)g * SZ + cc];
    }
}

extern "C" void kernel_launch(void* const* d_in, const int* in_sizes, int n_in,
                              void* d_out, int out_size, void* d_ws, size_t ws_size,
                              hipStream_t stream) {
    const float* x  = (const float*)d_in[0];
    const float* Wd = (const float*)d_in[1];
    const float* bd = (const float*)d_in[2];
    const float* Wu = (const float*)d_in[3];
    const float* bu = (const float*)d_in[4];
    const int* task = (const int*)d_in[5];
    float* out = (float*)d_out;

    char* ws = (char*)d_ws;
    int* idxb = (int*)ws;
    int* meta = (int*)(ws + 16384);
    float* H  = (float*)(ws + 16640);

    k_init<<<1, 64, 0, stream>>>(task, meta);
    k_hist<<<(BN + 255) / 256, 256, 0, stream>>>(task, meta);
    k_scan<<<1, 1, 0, stream>>>(meta);
    k_scatter<<<(BN + 255) / 256, 256, 0, stream>>>(task, meta, idxb);
    k_gemm1<<<NT * 256, 256, 0, stream>>>(x, Wd, bd, idxb, meta, H);
    k_gemm2<<<NT * 256 * 4, 256, 0, stream>>>(x, Wu, bu, idxb, meta, H, out);
    k_pass<<<256, 256, 0, stream>>>(x, idxb, meta, out);
}

// Round 2
// 219.968 us; speedup vs baseline: 1.7533x; 1.7533x over previous
//
#include <hip/hip_runtime.h>
#include <math.h>

#define BN 4096
#define SZ 2048
#define HIDN 128
#define NT 8
#define KS 8            // K-split factor for gemm1
#define KCH (SZ / KS)   // 256

// ws layout (bytes):
//   [0, 16384)         idxb    int[4096]  bucketed sample indices
//   [16384, 32768)     rowtask int[4096]  task id per bucketed row
//   [32768, 33280)     meta    int[]: [0..8]=cnt (8=invalid), [16..25]=offs,
//                      [32..40]=cursor, [48]=int64-flag
//   [33280, +2MB)      H float[4096*128]  adapter hidden (accumulated, then silu'd)

__global__ void k_init_zero(const int* __restrict__ task, int* __restrict__ meta,
                            float* __restrict__ H) {
    int tid = threadIdx.x;
    if (blockIdx.x == 0) {
        if (tid < 9) meta[tid] = 0;
        if (tid < 9) meta[32 + tid] = 0;
        if (tid < 64) {
            int v = task[2 * tid + 1];
            bool ok = (v == 0 || v == -1);
            unsigned long long m = __ballot(ok);
            if (tid == 0) meta[48] = (m == ~0ull) ? 1 : 0;
        }
    }
    // zero H: 4096*128 floats over 1024 blocks
    int i = blockIdx.x * 256 + tid;
    float4 z = {0.f, 0.f, 0.f, 0.f};
    float4* H4 = (float4*)H;
    for (int e = i; e < BN * HIDN / 4; e += 1024 * 256) H4[e] = z;
}

__device__ inline int bucket_of(const int* task, int b, int f64) {
    int t = f64 ? task[2 * b] : task[b];
    return (t < 0) ? 8 : (t > 7 ? 7 : t);
}

__global__ void k_hist(const int* __restrict__ task, int* __restrict__ meta) {
    int b = blockIdx.x * 256 + threadIdx.x;
    if (b >= BN) return;
    int f = meta[48];
    atomicAdd(&meta[bucket_of(task, b, f)], 1);
}

__global__ void k_scan(int* __restrict__ meta) {
    int s = 0;
    for (int i = 0; i < 9; i++) { meta[16 + i] = s; meta[32 + i] = s; s += meta[i]; }
    meta[16 + 9] = s;
}

__global__ void k_scatter(const int* __restrict__ task, int* __restrict__ meta,
                          int* __restrict__ idxb, int* __restrict__ rowtask) {
    int b = blockIdx.x * 256 + threadIdx.x;
    if (b >= BN) return;
    int f = meta[48];
    int bk = bucket_of(task, b, f);
    int p = atomicAdd(&meta[32 + bk], 1);
    idxb[p] = b;
    rowtask[p] = bk;
}

// GEMM1 split-K: H[base+r, h] += sum_{k in chunk} x[g(r), k] * Wd[t, k, h]
// grid = NT * 128tiles * KS; block 256. Tile = 32 rows; thread: 16 rows x 1 col.
__global__ __launch_bounds__(256) void k_gemm1(
    const float* __restrict__ x, const float* __restrict__ Wd,
    const int* __restrict__ idxb, const int* __restrict__ meta,
    float* __restrict__ H) {
    int bid = blockIdx.x;
    int ks = bid & (KS - 1);
    int tile = (bid >> 3) & 127;
    int t = bid >> 10;
    int n = meta[t];
    int r0 = tile * 32;
    if (r0 >= n) return;
    int base = meta[16 + t];

    __shared__ float XL[32][32];
    __shared__ int gidx[32];
    int tid = threadIdx.x;
    if (tid < 32) {
        int r = r0 + tid;
        gidx[tid] = idxb[base + (r < n ? r : n - 1)];
    }
    __syncthreads();

    int h = tid & 127;
    int sg = tid >> 7;  // rows sg*16 .. sg*16+15
    const float* wd = Wd + (size_t)t * SZ * HIDN + h;

    float acc[16];
#pragma unroll
    for (int i = 0; i < 16; i++) acc[i] = 0.f;

    int kbeg = ks * KCH;
    int rr = tid >> 3;          // 0..31 staging row
    int kq = (tid & 7) * 4;     // 0..28 staging k-quad
    for (int k0 = kbeg; k0 < kbeg + KCH; k0 += 32) {
        *reinterpret_cast<float4*>(&XL[rr][kq]) =
            *reinterpret_cast<const float4*>(&x[(size_t)gidx[rr] * SZ + k0 + kq]);
        __syncthreads();
#pragma unroll
        for (int kk4 = 0; kk4 < 8; kk4++) {
            float w0 = wd[(size_t)(k0 + kk4 * 4 + 0) * HIDN];
            float w1 = wd[(size_t)(k0 + kk4 * 4 + 1) * HIDN];
            float w2 = wd[(size_t)(k0 + kk4 * 4 + 2) * HIDN];
            float w3 = wd[(size_t)(k0 + kk4 * 4 + 3) * HIDN];
#pragma unroll
            for (int s = 0; s < 16; s++) {
                float4 xv = *reinterpret_cast<const float4*>(&XL[sg * 16 + s][kk4 * 4]);
                acc[s] = fmaf(xv.x, w0, acc[s]);
                acc[s] = fmaf(xv.y, w1, acc[s]);
                acc[s] = fmaf(xv.z, w2, acc[s]);
                acc[s] = fmaf(xv.w, w3, acc[s]);
            }
        }
        __syncthreads();
    }

#pragma unroll
    for (int s = 0; s < 16; s++) {
        int r = r0 + sg * 16 + s;
        if (r < n) atomicAdd(&H[(size_t)(base + r) * HIDN + h], acc[s]);
    }
}

// bias + silu over valid rows of H (in place)
__global__ void k_silu(const float* __restrict__ bd, const int* __restrict__ rowtask,
                       const int* __restrict__ meta, float* __restrict__ H) {
    int nv = meta[16 + 8];
    int i = blockIdx.x * 256 + threadIdx.x;  // one float4 per thread
    if (i >= nv * (HIDN / 4)) return;
    int r = i >> 5;           // 32 float4 per row
    int h4 = i & 31;
    int t = rowtask[r];
    float4 v = reinterpret_cast<float4*>(H)[i];
    float4 b = reinterpret_cast<const float4*>(bd)[t * 32 + h4];
    v.x += b.x; v.y += b.y; v.z += b.z; v.w += b.w;
    v.x = v.x / (1.f + __expf(-v.x));
    v.y = v.y / (1.f + __expf(-v.y));
    v.z = v.z / (1.f + __expf(-v.z));
    v.w = v.w / (1.f + __expf(-v.w));
    reinterpret_cast<float4*>(H)[i] = v;
}

// GEMM2: out[g(r), c] = x[g(r), c] + sum_h H[r, h] * Wu[t, h, c] + bu[t, c]
__global__ __launch_bounds__(256) void k_gemm2(
    const float* __restrict__ x, const float* __restrict__ Wu,
    const float* __restrict__ bu, const int* __restrict__ idxb,
    const int* __restrict__ meta, const float* __restrict__ H,
    float* __restrict__ out) {
    int bid = blockIdx.x;
    int t = bid >> 10;
    int tile = (bid >> 2) & 255;
    int cchunk = bid & 3;
    int n = meta[t];
    int r0 = tile * 16;
    if (r0 >= n) return;
    int base = meta[16 + t];

    __shared__ float HL[16][HIDN];
    __shared__ int gidx[16];
    int tid = threadIdx.x;
    if (tid < 16) {
        int r = r0 + tid;
        gidx[tid] = idxb[base + (r < n ? r : n - 1)];
    }
    {
        int hh = tid & 127, s2 = tid >> 7;
#pragma unroll
        for (int p = 0; p < 8; p++) {
            int s = p * 2 + s2;
            int r = r0 + s;
            HL[s][hh] = H[(size_t)(base + (r < n ? r : 0)) * HIDN + hh];
        }
    }
    __syncthreads();

    int c = cchunk * 512 + tid;
    const float* wu = Wu + (size_t)t * HIDN * SZ;

    float acc0[16], acc1[16];
#pragma unroll
    for (int s = 0; s < 16; s++) { acc0[s] = 0.f; acc1[s] = 0.f; }

    for (int h4 = 0; h4 < HIDN / 4; h4++) {
        float w00 = wu[(size_t)(h4 * 4 + 0) * SZ + c];
        float w01 = wu[(size_t)(h4 * 4 + 1) * SZ + c];
        float w02 = wu[(size_t)(h4 * 4 + 2) * SZ + c];
        float w03 = wu[(size_t)(h4 * 4 + 3) * SZ + c];
        float w10 = wu[(size_t)(h4 * 4 + 0) * SZ + c + 256];
        float w11 = wu[(size_t)(h4 * 4 + 1) * SZ + c + 256];
        float w12 = wu[(size_t)(h4 * 4 + 2) * SZ + c + 256];
        float w13 = wu[(size_t)(h4 * 4 + 3) * SZ + c + 256];
#pragma unroll
        for (int s = 0; s < 16; s++) {
            float4 hv = *reinterpret_cast<const float4*>(&HL[s][h4 * 4]);
            acc0[s] = fmaf(hv.x, w00, acc0[s]);
            acc0[s] = fmaf(hv.y, w01, acc0[s]);
            acc0[s] = fmaf(hv.z, w02, acc0[s]);
            acc0[s] = fmaf(hv.w, w03, acc0[s]);
            acc1[s] = fmaf(hv.x, w10, acc1[s]);
            acc1[s] = fmaf(hv.y, w11, acc1[s]);
            acc1[s] = fmaf(hv.z, w12, acc1[s]);
            acc1[s] = fmaf(hv.w, w13, acc1[s]);
        }
    }

    float b0 = bu[t * SZ + c];
    float b1 = bu[t * SZ + c + 256];
#pragma unroll
    for (int s = 0; s < 16; s++) {
        int r = r0 + s;
        if (r < n) {
            size_t g = (size_t)gidx[s] * SZ;
            out[g + c]       = x[g + c] + acc0[s] + b0;
            out[g + c + 256] = x[g + c + 256] + acc1[s] + b1;
        }
    }
}

// Passthrough for invalid task ids (bucket 8): out = x
__global__ void k_pass(const float* __restrict__ x, const int* __restrict__ idxb,
                       const int* __restrict__ meta, float* __restrict__ out) {
    int n8 = meta[8];
    if (n8 == 0) return;
    long total = (long)n8 * SZ;
    int base8 = meta[16 + 8];
    for (long i = (long)blockIdx.x * blockDim.x + threadIdx.x; i < total;
         i += (long)gridDim.x * blockDim.x) {
        int r = (int)(i >> 11);
        int cc = (int)(i & (SZ - 1));
        int g = idxb[base8 + r];
        out[(size_t)g * SZ + cc] = x[(size_t)g * SZ + cc];
    }
}

extern "C" void kernel_launch(void* const* d_in, const int* in_sizes, int n_in,
                              void* d_out, int out_size, void* d_ws, size_t ws_size,
                              hipStream_t stream) {
    const float* x  = (const float*)d_in[0];
    const float* Wd = (const float*)d_in[1];
    const float* bd = (const float*)d_in[2];
    const float* Wu = (const float*)d_in[3];
    const float* bu = (const float*)d_in[4];
    const int* task = (const int*)d_in[5];
    float* out = (float*)d_out;

    char* ws = (char*)d_ws;
    int* idxb    = (int*)ws;
    int* rowtask = (int*)(ws + 16384);
    int* meta    = (int*)(ws + 32768);
    float* H     = (float*)(ws + 33280);

    k_init_zero<<<1024, 256, 0, stream>>>(task, meta, H);
    k_hist<<<(BN + 255) / 256, 256, 0, stream>>>(task, meta);
    k_scan<<<1, 1, 0, stream>>>(meta);
    k_scatter<<<(BN + 255) / 256, 256, 0, stream>>>(task, meta, idxb, rowtask);
    k_gemm1<<<NT * 128 * KS, 256, 0, stream>>>(x, Wd, idxb, meta, H);
    k_silu<<<(BN * HIDN / 4 + 255) / 256, 256, 0, stream>>>(bd, rowtask, meta, H);
    k_gemm2<<<NT * 256 * 4, 256, 0, stream>>>(x, Wu, bu, idxb, meta, H, out);
    k_pass<<<256, 256, 0, stream>>>(x, idxb, meta, out);
}

// Round 3
// 116.848 us; speedup vs baseline: 3.3006x; 1.8825x over previous
//
#include <hip/hip_runtime.h>

#define BN 4096
#define SZ 2048
#define HIDN 128
#define NT 8
#define KS 8
#define KCH (SZ / KS)

typedef __bf16 bf16_t;
typedef bf16_t bf16x4 __attribute__((ext_vector_type(4)));
typedef bf16_t bf16x8 __attribute__((ext_vector_type(8)));
typedef float f32x4 __attribute__((ext_vector_type(4)));

__device__ inline unsigned short f2b(float f) {
    unsigned u = __builtin_bit_cast(unsigned, f);
    return (unsigned short)((u + 0x7fffu + ((u >> 16) & 1u)) >> 16);
}

// ws layout: idxb int[4096] @0 | rowtask int[4096] @16K | meta @32K |
//            H f32[4096*128] @33280 | Hb bf16[4096*128] | WdT bf16[8*128*2048] |
//            WuT bf16[8*2048*128]   (total ~11.6 MB)

// ---- bucketing: hist + scan + scatter in one block ----
__global__ __launch_bounds__(1024) void k_bucket(const int* __restrict__ task,
                                                 int* __restrict__ meta,
                                                 int* __restrict__ idxb,
                                                 int* __restrict__ rowtask) {
    __shared__ int cnt[9], off[10], cur[9], sflag;
    int tid = threadIdx.x;
    if (tid < 9) cnt[tid] = 0;
    if (tid < 64) {
        int v = task[2 * tid + 1];
        bool ok = (v == 0 || v == -1);   // int64 detection via sign-extension words
        unsigned long long m = __ballot(ok);
        if (tid == 0) sflag = (m == ~0ull) ? 1 : 0;
    }
    __syncthreads();
    int f = sflag;
    int bks[4];
#pragma unroll
    for (int i = 0; i < 4; i++) {
        int b = i * 1024 + tid;
        int t = f ? task[2 * b] : task[b];
        int bk = (t < 0) ? 8 : (t > 7 ? 7 : t);
        bks[i] = bk;
        atomicAdd(&cnt[bk], 1);
    }
    __syncthreads();
    if (tid == 0) {
        int s = 0;
        for (int i = 0; i < 9; i++) { off[i] = s; cur[i] = s; s += cnt[i]; }
        off[9] = s;
    }
    __syncthreads();
#pragma unroll
    for (int i = 0; i < 4; i++) {
        int b = i * 1024 + tid;
        int p = atomicAdd(&cur[bks[i]], 1);
        idxb[p] = b;
        rowtask[p] = bks[i];
    }
    if (tid < 9) { meta[tid] = cnt[tid]; meta[16 + tid] = off[tid]; }
    if (tid == 9) meta[16 + 9] = off[9];
    if (tid == 10) meta[48] = sflag;
}

// ---- weight transpose fp32->bf16 (+ zero H) ----
// bid<2048: Wd [t][2048][128] -> WdT [t][128][2048]; else Wu [t][128][2048] -> WuT [t][2048][128]
__global__ __launch_bounds__(256) void k_tr(const float* __restrict__ Wd,
                                            const float* __restrict__ Wu,
                                            unsigned short* __restrict__ WdT,
                                            unsigned short* __restrict__ WuT,
                                            float* __restrict__ H) {
    int bid = blockIdx.x;
    int tid = threadIdx.x;
    if (bid < 1024) {  // zero H (2 MB)
        float4* H4 = (float4*)H;
        float4 z = {0.f, 0.f, 0.f, 0.f};
        H4[bid * 512 + tid] = z;
        H4[bid * 512 + 256 + tid] = z;
    }
    __shared__ float t32[32][33];
    const float* in;
    unsigned short* outp;
    int R, C, rt, ct;
    if (bid < 2048) {
        int t = bid >> 8, rem = bid & 255;
        R = 2048; C = 128; rt = rem >> 2; ct = rem & 3;
        in = Wd + (size_t)t * R * C;
        outp = WdT + (size_t)t * R * C;
    } else {
        int lb = bid - 2048;
        int t = lb >> 8, rem = lb & 255;
        R = 128; C = 2048; rt = rem >> 6; ct = rem & 63;
        in = Wu + (size_t)t * R * C;
        outp = WuT + (size_t)t * R * C;
    }
    int tx = tid & 31, ty = tid >> 5;
#pragma unroll
    for (int i = 0; i < 4; i++)
        t32[ty + 8 * i][tx] = in[(size_t)(rt * 32 + ty + 8 * i) * C + ct * 32 + tx];
    __syncthreads();
#pragma unroll
    for (int i = 0; i < 4; i++)
        outp[(size_t)(ct * 32 + ty + 8 * i) * R + rt * 32 + tx] = f2b(t32[tx][ty + 8 * i]);
}

// ---- GEMM1 (MFMA, split-K): H[base+r][h] += x[g(r)][k-chunk] . Wd[t][k][h] ----
// block 256 = 4 waves (2 row-groups x 2 col-groups); tile 32 rows x 128 h
__global__ __launch_bounds__(256) void k_gemm1(const float* __restrict__ x,
                                               const unsigned short* __restrict__ WdT,
                                               const int* __restrict__ idxb,
                                               const int* __restrict__ meta,
                                               float* __restrict__ H) {
    int bid = blockIdx.x;
    int ks = bid & (KS - 1);
    int tile = (bid >> 3) & 127;
    int t = bid >> 10;
    int n = meta[t];
    int r0 = tile * 32;
    if (r0 >= n) return;
    int base = meta[16 + t];

    int tid = threadIdx.x;
    int lane = tid & 63, w = tid >> 6;
    int rg = w & 1, cg = w >> 1;
    int lr = lane & 15, lq = lane >> 4;

    int ar = r0 + rg * 16 + lr;
    int g = idxb[base + (ar < n ? ar : n - 1)];
    const float* xrow = x + (size_t)g * SZ;
    const bf16_t* wdt = (const bf16_t*)WdT + (size_t)t * HIDN * SZ;

    f32x4 acc[4] = {};
    int k = ks * KCH + 4 * lq;
#pragma unroll 2
    for (int it = 0; it < KCH / 32; it++, k += 32) {
        float4 xlo = *(const float4*)(xrow + k);
        float4 xhi = *(const float4*)(xrow + k + 16);
        bf16x8 a;
        a[0] = (bf16_t)xlo.x; a[1] = (bf16_t)xlo.y; a[2] = (bf16_t)xlo.z; a[3] = (bf16_t)xlo.w;
        a[4] = (bf16_t)xhi.x; a[5] = (bf16_t)xhi.y; a[6] = (bf16_t)xhi.z; a[7] = (bf16_t)xhi.w;
#pragma unroll
        for (int fi = 0; fi < 4; fi++) {
            const bf16_t* wp = wdt + (size_t)(cg * 64 + fi * 16 + lr) * SZ + k;
            bf16x4 blo = *(const bf16x4*)wp;
            bf16x4 bhi = *(const bf16x4*)(wp + 16);
            bf16x8 b;
            b[0] = blo[0]; b[1] = blo[1]; b[2] = blo[2]; b[3] = blo[3];
            b[4] = bhi[0]; b[5] = bhi[1]; b[6] = bhi[2]; b[7] = bhi[3];
            acc[fi] = __builtin_amdgcn_mfma_f32_16x16x32_bf16(a, b, acc[fi], 0, 0, 0);
        }
    }
#pragma unroll
    for (int fi = 0; fi < 4; fi++) {
        int h = cg * 64 + fi * 16 + lr;
#pragma unroll
        for (int reg = 0; reg < 4; reg++) {
            int r = r0 + rg * 16 + 4 * lq + reg;
            if (r < n) atomicAdd(&H[(size_t)(base + r) * HIDN + h], acc[fi][reg]);
        }
    }
}

// ---- bias + silu + bf16 pack ----
__global__ void k_silu(const float* __restrict__ bd, const int* __restrict__ rowtask,
                       const float* __restrict__ H, unsigned short* __restrict__ Hb) {
    int i = blockIdx.x * 256 + threadIdx.x;
    if (i >= BN * HIDN / 4) return;
    int r = i >> 5;
    int t = rowtask[r]; if (t > 7) t = 7;
    float4 v = ((const float4*)H)[i];
    float4 b = ((const float4*)bd)[t * 32 + (i & 31)];
    v.x += b.x; v.y += b.y; v.z += b.z; v.w += b.w;
    v.x = v.x / (1.f + __expf(-v.x));
    v.y = v.y / (1.f + __expf(-v.y));
    v.z = v.z / (1.f + __expf(-v.z));
    v.w = v.w / (1.f + __expf(-v.w));
    ushort4 o = {f2b(v.x), f2b(v.y), f2b(v.z), f2b(v.w)};
    ((ushort4*)Hb)[i] = o;
}

// ---- GEMM2 (MFMA): out[g(r)][c] = x[g(r)][c] + Hb[r][:] . Wu[t][:][c] + bu[t][c] ----
__global__ __launch_bounds__(256) void k_gemm2(const float* __restrict__ x,
                                               const unsigned short* __restrict__ WuT,
                                               const float* __restrict__ bu,
                                               const unsigned short* __restrict__ Hb,
                                               const int* __restrict__ idxb,
                                               const int* __restrict__ meta,
                                               float* __restrict__ out) {
    int bid = blockIdx.x;
    int cchunk = bid & 15;
    int tile = (bid >> 4) & 127;
    int t = bid >> 11;
    int n = meta[t];
    int r0 = tile * 32;
    if (r0 >= n) return;
    int base = meta[16 + t];

    int tid = threadIdx.x;
    int lane = tid & 63, w = tid >> 6;
    int rg = w & 1, cg = w >> 1;
    int lr = lane & 15, lq = lane >> 4;

    int ar = r0 + rg * 16 + lr;
    const bf16_t* hrow = (const bf16_t*)Hb + (size_t)(base + (ar < n ? ar : n - 1)) * HIDN;
    const bf16_t* wut = (const bf16_t*)WuT + (size_t)t * SZ * HIDN;
    int c_base = cchunk * 128 + cg * 64;

    f32x4 acc[4] = {};
#pragma unroll
    for (int k0 = 0; k0 < HIDN; k0 += 32) {
        int ka = k0 + 4 * lq;
        bf16x4 alo = *(const bf16x4*)(hrow + ka);
        bf16x4 ahi = *(const bf16x4*)(hrow + ka + 16);
        bf16x8 a;
        a[0] = alo[0]; a[1] = alo[1]; a[2] = alo[2]; a[3] = alo[3];
        a[4] = ahi[0]; a[5] = ahi[1]; a[6] = ahi[2]; a[7] = ahi[3];
#pragma unroll
        for (int fi = 0; fi < 4; fi++) {
            const bf16_t* wp = wut + (size_t)(c_base + fi * 16 + lr) * HIDN + ka;
            bf16x4 blo = *(const bf16x4*)wp;
            bf16x4 bhi = *(const bf16x4*)(wp + 16);
            bf16x8 b;
            b[0] = blo[0]; b[1] = blo[1]; b[2] = blo[2]; b[3] = blo[3];
            b[4] = bhi[0]; b[5] = bhi[1]; b[6] = bhi[2]; b[7] = bhi[3];
            acc[fi] = __builtin_amdgcn_mfma_f32_16x16x32_bf16(a, b, acc[fi], 0, 0, 0);
        }
    }

    int gr[4];
#pragma unroll
    for (int reg = 0; reg < 4; reg++) {
        int r = r0 + rg * 16 + 4 * lq + reg;
        gr[reg] = (r < n) ? idxb[base + r] : -1;
    }
#pragma unroll
    for (int fi = 0; fi < 4; fi++) {
        int c = c_base + fi * 16 + lr;
        float bb = bu[t * SZ + c];
#pragma unroll
        for (int reg = 0; reg < 4; reg++) {
            if (gr[reg] >= 0) {
                size_t o = (size_t)gr[reg] * SZ + c;
                out[o] = x[o] + acc[fi][reg] + bb;
            }
        }
    }
}

// ---- passthrough for invalid task ids ----
__global__ void k_pass(const float* __restrict__ x, const int* __restrict__ idxb,
                       const int* __restrict__ meta, float* __restrict__ out) {
    int n8 = meta[8];
    if (n8 == 0) return;
    long total = (long)n8 * SZ;
    int base8 = meta[16 + 8];
    for (long i = (long)blockIdx.x * blockDim.x + threadIdx.x; i < total;
         i += (long)gridDim.x * blockDim.x) {
        int r = (int)(i >> 11);
        int cc = (int)(i & (SZ - 1));
        int g = idxb[base8 + r];
        out[(size_t)g * SZ + cc] = x[(size_t)g * SZ + cc];
    }
}

extern "C" void kernel_launch(void* const* d_in, const int* in_sizes, int n_in,
                              void* d_out, int out_size, void* d_ws, size_t ws_size,
                              hipStream_t stream) {
    const float* x  = (const float*)d_in[0];
    const float* Wd = (const float*)d_in[1];
    const float* bd = (const float*)d_in[2];
    const float* Wu = (const float*)d_in[3];
    const float* bu = (const float*)d_in[4];
    const int* task = (const int*)d_in[5];
    float* out = (float*)d_out;

    char* ws = (char*)d_ws;
    int* idxb    = (int*)ws;
    int* rowtask = (int*)(ws + 16384);
    int* meta    = (int*)(ws + 32768);
    float* H     = (float*)(ws + 33280);
    unsigned short* Hb  = (unsigned short*)(ws + 33280 + 2097152);
    unsigned short* WdT = (unsigned short*)(ws + 33280 + 2097152 + 1048576);
    unsigned short* WuT = (unsigned short*)(ws + 33280 + 2097152 + 1048576 + 4194304);

    k_bucket<<<1, 1024, 0, stream>>>(task, meta, idxb, rowtask);
    k_tr<<<4096, 256, 0, stream>>>(Wd, Wu, WdT, WuT, H);
    k_gemm1<<<NT * 128 * KS, 256, 0, stream>>>(x, WdT, idxb, meta, H);
    k_silu<<<BN * HIDN / 4 / 256, 256, 0, stream>>>(bd, rowtask, H, Hb);
    k_gemm2<<<NT << 11, 256, 0, stream>>>(x, WuT, bu, Hb, idxb, meta, out);
    k_pass<<<256, 256, 0, stream>>>(x, idxb, meta, out);
}

// Round 4
// 74.063 us; speedup vs baseline: 5.2073x; 1.5777x over previous
//
#include <hip/hip_runtime.h>

#define BN 4096
#define SZ 2048
#define HIDN 128
#define NT 8
#define KS 8
#define KCH (SZ / KS)        // 256
#define PADROWS 4384         // 4096 + 9*32 padding
#define PADTILES (PADROWS / 16)  // 274

typedef __bf16 bf16_t;
typedef bf16_t bf16x8 __attribute__((ext_vector_type(8)));
typedef float f32x4 __attribute__((ext_vector_type(4)));

__device__ inline bf16_t f2b(float f) {
    unsigned u = __builtin_bit_cast(unsigned, f);
    unsigned short s = (unsigned short)((u + 0x7fffu + ((u >> 16) & 1u)) >> 16);
    return __builtin_bit_cast(bf16_t, s);
}

// ws layout (bytes):
//   idxb    int[PADROWS]  @0          (padding slots unwritten -> all reads clamped)
//   rowtask int[PADROWS]  @17664
//   meta                  @35328      [0..8]=cnt, [16..25]=padded offs, [48]=i64 flag
//   H   f32 [PADROWS*128] @35840
//   HbP bf16 frag-packed  @2280448    [rt][kf][lane][8]
//   WdP bf16 frag-packed  @3402752    [t][hf(8)][kt(64)][lane][8]
//   WuP bf16 frag-packed  @7597056    [t][cf(128)][kf(4)][lane][8]

// ---- bucketing (offsets padded to 32 rows) ----
__global__ __launch_bounds__(1024) void k_bucket(const int* __restrict__ task,
                                                 int* __restrict__ meta,
                                                 int* __restrict__ idxb,
                                                 int* __restrict__ rowtask) {
    __shared__ int cnt[9], off[10], cur[9], sflag;
    int tid = threadIdx.x;
    if (tid < 9) cnt[tid] = 0;
    if (tid < 64) {
        int v = task[2 * tid + 1];
        bool ok = (v == 0 || v == -1);   // int64 detection via sign-extension words
        unsigned long long m = __ballot(ok);
        if (tid == 0) sflag = (m == ~0ull) ? 1 : 0;
    }
    __syncthreads();
    int f = sflag;
    int bks[4];
#pragma unroll
    for (int i = 0; i < 4; i++) {
        int b = i * 1024 + tid;
        int t = f ? task[2 * b] : task[b];
        int bk = (t < 0) ? 8 : (t > 7 ? 7 : t);
        bks[i] = bk;
        atomicAdd(&cnt[bk], 1);
    }
    __syncthreads();
    if (tid == 0) {
        int s = 0;
        for (int i = 0; i < 9; i++) { off[i] = s; cur[i] = s; s += (cnt[i] + 31) & ~31; }
        off[9] = s;
    }
    __syncthreads();
#pragma unroll
    for (int i = 0; i < 4; i++) {
        int b = i * 1024 + tid;
        int p = atomicAdd(&cur[bks[i]], 1);
        idxb[p] = b;
        rowtask[p] = bks[i];
    }
    if (tid < 9) meta[tid] = cnt[tid];
    if (tid >= 16 && tid < 26) meta[tid] = off[tid - 16];
    if (tid == 48) meta[48] = sflag;
}

// ---- weight pack: fp32 -> bf16 fragment layout (+ zero H) ----
// bid<512: Wd (t=bid>>6, kt=bid&63)   tile = k[32] x h[128]
// else   : Wu (t, kf=rem>>4, cch=rem&15) tile = k[32] x c[128]
__global__ __launch_bounds__(256) void k_pack(const float* __restrict__ Wd,
                                              const float* __restrict__ Wu,
                                              bf16_t* __restrict__ WdP,
                                              bf16_t* __restrict__ WuP,
                                              float* __restrict__ H) {
    int bid = blockIdx.x, tid = threadIdx.x;
    {   // zero H (PADROWS*128 f32)
        int i = bid * 256 + tid;
        if (i < PADROWS * HIDN / 4) {
            float4 z = {0.f, 0.f, 0.f, 0.f};
            ((float4*)H)[i] = z;
        }
    }
    __shared__ float tile[32][132];
    const float* src;
    bf16_t* dst;  // fragment base for this tile
    int fragstride;  // elements between consecutive "hf" fragments at dst
    size_t rowstride;
    if (bid < 512) {
        int t = bid >> 6, kt = bid & 63;
        src = Wd + ((size_t)t * SZ + kt * 32) * HIDN;
        rowstride = HIDN;
        dst = WdP + ((size_t)(t * 8) * 64 + kt) * 512;
        fragstride = 64 * 512;   // hf stride: 64 kt-frags apart
    } else {
        int lb = bid - 512;
        int t = lb >> 6, rem = lb & 63;
        int kf = rem >> 4, cch = rem & 15;
        src = Wu + ((size_t)t * HIDN + kf * 32) * SZ + cch * 128;
        rowstride = SZ;
        dst = WuP + ((size_t)(t * 128 + cch * 8) * 4 + kf) * 512;
        fragstride = 4 * 512;    // cf stride: 4 kf-frags apart
    }
#pragma unroll
    for (int i = 0; i < 4; i++) {
        int row = (tid >> 5) + 8 * i, quad = tid & 31;
        float4 v = *(const float4*)(src + (size_t)row * rowstride + quad * 4);
        tile[row][quad * 4 + 0] = v.x; tile[row][quad * 4 + 1] = v.y;
        tile[row][quad * 4 + 2] = v.z; tile[row][quad * 4 + 3] = v.w;
    }
    __syncthreads();
    int w = tid >> 6, lane = tid & 63, lr = lane & 15, lq = lane >> 4;
#pragma unroll
    for (int ii = 0; ii < 2; ii++) {
        int hf = w * 2 + ii;
        bf16x8 o;
#pragma unroll
        for (int j = 0; j < 8; j++) {
            int kloc = (j < 4) ? (4 * lq + j) : (16 + 4 * lq + j - 4);
            o[j] = f2b(tile[kloc][hf * 16 + lr]);
        }
        *(bf16x8*)(dst + (size_t)hf * fragstride + lane * 8) = o;
    }
}

// ---- GEMM1 (split-K): H[base+r][h] += x[g(r)][kchunk] . Wd[t][k][h] ----
__global__ __launch_bounds__(256) void k_gemm1(const float* __restrict__ x,
                                               const bf16_t* __restrict__ WdP,
                                               const int* __restrict__ idxb,
                                               const int* __restrict__ meta,
                                               float* __restrict__ H) {
    int bid = blockIdx.x;
    int ks = bid & 7, tile = (bid >> 3) & 127, t = bid >> 10;
    int n = meta[t];
    int r0 = tile * 32;
    if (r0 >= n) return;
    int base = meta[16 + t];
    int tid = threadIdx.x, lane = tid & 63, w = tid >> 6;
    int rg = w & 1, cg = w >> 1, lr = lane & 15, lq = lane >> 4;

    int br = r0 + rg * 16 + lr;
    int g = idxb[base + (br < n ? br : n - 1)];
    const float* xrow = x + (size_t)g * SZ + ks * KCH + 4 * lq;
    const bf16_t* wb = WdP + ((size_t)(t * 8 + cg * 4) * 64 + ks * 8) * 512 + lane * 8;

    f32x4 acc[4] = {};
#pragma unroll
    for (int kfi = 0; kfi < 8; kfi++) {
        float4 lo = *(const float4*)(xrow + kfi * 32);
        float4 hi = *(const float4*)(xrow + kfi * 32 + 16);
        bf16x8 a;
        a[0] = f2b(lo.x); a[1] = f2b(lo.y); a[2] = f2b(lo.z); a[3] = f2b(lo.w);
        a[4] = f2b(hi.x); a[5] = f2b(hi.y); a[6] = f2b(hi.z); a[7] = f2b(hi.w);
#pragma unroll
        for (int hf = 0; hf < 4; hf++) {
            bf16x8 b = *(const bf16x8*)(wb + (size_t)(hf * 64 + kfi) * 512);
            acc[hf] = __builtin_amdgcn_mfma_f32_16x16x32_bf16(a, b, acc[hf], 0, 0, 0);
        }
    }
#pragma unroll
    for (int hf = 0; hf < 4; hf++) {
        int h = cg * 64 + hf * 16 + lr;
#pragma unroll
        for (int reg = 0; reg < 4; reg++) {
            int r = r0 + rg * 16 + 4 * lq + reg;
            if (r < n) atomicAdd(&H[(size_t)(base + r) * HIDN + h], acc[hf][reg]);
        }
    }
}

// ---- bias + silu + pack Hb into A-fragment layout ----
__global__ __launch_bounds__(256) void k_silu(const float* __restrict__ bd,
                                              const int* __restrict__ rowtask,
                                              const float* __restrict__ H,
                                              bf16_t* __restrict__ HbP) {
    int rt = blockIdx.x;                      // 0..PADTILES-1
    int w = threadIdx.x >> 6, lane = threadIdx.x & 63;
    int kf = w, lr = lane & 15, lq = lane >> 4;
    int R = rt * 16 + lr;
    int t = rowtask[R];
    t = t < 0 ? 0 : (t > 7 ? 7 : t);
    const float* hp = H + (size_t)R * HIDN + kf * 32 + 4 * lq;
    float4 lo = *(const float4*)hp;
    float4 hi = *(const float4*)(hp + 16);
    const float* bp = bd + t * HIDN + kf * 32 + 4 * lq;
    float4 blo = *(const float4*)bp;
    float4 bhi = *(const float4*)(bp + 16);
    float v[8] = {lo.x + blo.x, lo.y + blo.y, lo.z + blo.z, lo.w + blo.w,
                  hi.x + bhi.x, hi.y + bhi.y, hi.z + bhi.z, hi.w + bhi.w};
    bf16x8 o;
#pragma unroll
    for (int j = 0; j < 8; j++) o[j] = f2b(v[j] / (1.f + __expf(-v[j])));
    *(bf16x8*)(HbP + ((size_t)(rt * 4 + kf) * 64 + lane) * 8) = o;
}

// ---- GEMM2: out[g(r)][c] = x[g(r)][c] + Hb[r][:] . Wu[t][:][c] + bu[t][c] ----
__global__ __launch_bounds__(256) void k_gemm2(const float* __restrict__ x,
                                               const bf16_t* __restrict__ WuP,
                                               const float* __restrict__ bu,
                                               const bf16_t* __restrict__ HbP,
                                               const int* __restrict__ idxb,
                                               const int* __restrict__ meta,
                                               float* __restrict__ out) {
    int bid = blockIdx.x;
    int cchunk = bid & 7, tile = (bid >> 3) & 127, t = bid >> 10;
    int n = meta[t];
    int r0 = tile * 32;
    if (r0 >= n) return;
    int base = meta[16 + t];
    int tid = threadIdx.x, lane = tid & 63, w = tid >> 6;
    int wr = w & 1, wc = w >> 1, lr = lane & 15, lq = lane >> 4;

    int rt = (base + r0) / 16 + wr;           // base is 32-aligned
    const bf16_t* ap = HbP + (size_t)rt * 4 * 512 + lane * 8;
    bf16x8 a[4];
#pragma unroll
    for (int kf = 0; kf < 4; kf++) a[kf] = *(const bf16x8*)(ap + kf * 512);

    const bf16_t* bp = WuP + ((size_t)(t * 128 + cchunk * 16 + wc * 8) * 4) * 512 + lane * 8;
    f32x4 acc[8] = {};
#pragma unroll
    for (int cf = 0; cf < 8; cf++) {
#pragma unroll
        for (int kf = 0; kf < 4; kf++) {
            bf16x8 b = *(const bf16x8*)(bp + (size_t)(cf * 4 + kf) * 512);
            acc[cf] = __builtin_amdgcn_mfma_f32_16x16x32_bf16(a[kf], b, acc[cf], 0, 0, 0);
        }
    }

    int gr[4];
#pragma unroll
    for (int reg = 0; reg < 4; reg++) {
        int r = r0 + wr * 16 + 4 * lq + reg;
        gr[reg] = (r < n) ? idxb[base + r] : -1;
    }
#pragma unroll
    for (int cf = 0; cf < 8; cf++) {
        int c = cchunk * 256 + wc * 128 + cf * 16 + lr;
        float bb = bu[t * SZ + c];
#pragma unroll
        for (int reg = 0; reg < 4; reg++) {
            if (gr[reg] >= 0) {
                size_t o = (size_t)gr[reg] * SZ + c;
                out[o] = x[o] + acc[cf][reg] + bb;
            }
        }
    }
}

// ---- passthrough for invalid task ids ----
__global__ void k_pass(const float* __restrict__ x, const int* __restrict__ idxb,
                       const int* __restrict__ meta, float* __restrict__ out) {
    int n8 = meta[8];
    if (n8 == 0) return;
    long total = (long)n8 * SZ;
    int base8 = meta[16 + 8];
    for (long i = (long)blockIdx.x * blockDim.x + threadIdx.x; i < total;
         i += (long)gridDim.x * blockDim.x) {
        int r = (int)(i >> 11);
        int cc = (int)(i & (SZ - 1));
        int g = idxb[base8 + r];
        out[(size_t)g * SZ + cc] = x[(size_t)g * SZ + cc];
    }
}

extern "C" void kernel_launch(void* const* d_in, const int* in_sizes, int n_in,
                              void* d_out, int out_size, void* d_ws, size_t ws_size,
                              hipStream_t stream) {
    const float* x  = (const float*)d_in[0];
    const float* Wd = (const float*)d_in[1];
    const float* bd = (const float*)d_in[2];
    const float* Wu = (const float*)d_in[3];
    const float* bu = (const float*)d_in[4];
    const int* task = (const int*)d_in[5];
    float* out = (float*)d_out;

    char* ws = (char*)d_ws;
    int* idxb    = (int*)ws;
    int* rowtask = (int*)(ws + 17664);
    int* meta    = (int*)(ws + 35328);
    float* H     = (float*)(ws + 35840);
    bf16_t* HbP  = (bf16_t*)(ws + 2280448);
    bf16_t* WdP  = (bf16_t*)(ws + 3402752);
    bf16_t* WuP  = (bf16_t*)(ws + 7597056);

    k_bucket<<<1, 1024, 0, stream>>>(task, meta, idxb, rowtask);
    k_pack<<<1024, 256, 0, stream>>>(Wd, Wu, WdP, WuP, H);
    k_gemm1<<<NT * 128 * KS, 256, 0, stream>>>(x, WdP, idxb, meta, H);
    k_silu<<<PADTILES, 256, 0, stream>>>(bd, rowtask, H, HbP);
    k_gemm2<<<NT * 128 * 8, 256, 0, stream>>>(x, WuP, bu, HbP, idxb, meta, out);
    k_pass<<<256, 256, 0, stream>>>(x, idxb, meta, out);
}

// Round 6
// 69.329 us; speedup vs baseline: 5.5629x; 1.0683x over previous
//
#include <hip/hip_runtime.h>

#define BN 4096
#define SZ 2048
#define HIDN 128
#define NT 8
#define KS 4
#define KCH (SZ / KS)        // 512
#define PADROWS 4384         // 4096 + 9*32 padding
#define PADTILES (PADROWS / 16)  // 274

typedef __bf16 bf16_t;
typedef bf16_t bf16x8 __attribute__((ext_vector_type(8)));
typedef float f32x4 __attribute__((ext_vector_type(4)));

__device__ inline bf16_t f2b(float f) {
    unsigned u = __builtin_bit_cast(unsigned, f);
    unsigned short s = (unsigned short)((u + 0x7fffu + ((u >> 16) & 1u)) >> 16);
    return __builtin_bit_cast(bf16_t, s);
}

// ws layout (bytes):
//   idxb    int[PADROWS]  @0
//   rowtask int[PADROWS]  @17664
//   meta                  @35328   [0..8]=cnt, [16..25]=padded offs, [48]=i64 flag
//   H   f32 [PADROWS*128] @35840
//   HbP bf16 frag-packed  @2280448 [rt][kf][lane][8]
//   WdP bf16 frag-packed  @3402752 [t][hf(8)][kt(64)][lane][8]
//   WuP bf16 frag-packed  @7597056 [t][cf(128)][kf(4)][lane][8]

// ---- prep: blocks 0..1023 pack weights + zero H; block 1024 does bucketing ----
__global__ __launch_bounds__(256) void k_prep(const float* __restrict__ Wd,
                                              const float* __restrict__ Wu,
                                              const int* __restrict__ task,
                                              bf16_t* __restrict__ WdP,
                                              bf16_t* __restrict__ WuP,
                                              float* __restrict__ H,
                                              int* __restrict__ meta,
                                              int* __restrict__ idxb,
                                              int* __restrict__ rowtask) {
    int bid = blockIdx.x, tid = threadIdx.x;
    if (bid == 1024) {  // ---- bucketing (offsets padded to 32) ----
        __shared__ int cnt[9], off[10], cur[9], sflag;
        if (tid < 9) cnt[tid] = 0;
        if (tid < 64) {
            int v = task[2 * tid + 1];
            bool ok = (v == 0 || v == -1);   // int64 detection via sign-ext words
            unsigned long long m = __ballot(ok);
            if (tid == 0) sflag = (m == ~0ull) ? 1 : 0;
        }
        __syncthreads();
        int f = sflag;
        int bks[16];
#pragma unroll
        for (int i = 0; i < 16; i++) {
            int b = i * 256 + tid;
            int t = f ? task[2 * b] : task[b];
            bks[i] = (t < 0) ? 8 : (t > 7 ? 7 : t);
            atomicAdd(&cnt[bks[i]], 1);
        }
        __syncthreads();
        if (tid == 0) {
            int s = 0;
            for (int i = 0; i < 9; i++) { off[i] = s; cur[i] = s; s += (cnt[i] + 31) & ~31; }
            off[9] = s;
        }
        __syncthreads();
#pragma unroll
        for (int i = 0; i < 16; i++) {
            int b = i * 256 + tid;
            int p = atomicAdd(&cur[bks[i]], 1);
            idxb[p] = b;
            rowtask[p] = bks[i];
        }
        if (tid < 9) meta[tid] = cnt[tid];
        if (tid >= 16 && tid < 26) meta[tid] = off[tid - 16];
        if (tid == 48) meta[48] = sflag;
        return;
    }
    {   // zero H
        int i = bid * 256 + tid;
        if (i < PADROWS * HIDN / 4) {
            f32x4 z = {0.f, 0.f, 0.f, 0.f};
            ((f32x4*)H)[i] = z;
        }
    }
    __shared__ float tile[32][132];
    const float* src;
    bf16_t* dst;
    int fragstride;
    size_t rowstride;
    if (bid < 512) {
        int t = bid >> 6, kt = bid & 63;
        src = Wd + ((size_t)t * SZ + kt * 32) * HIDN;
        rowstride = HIDN;
        dst = WdP + ((size_t)(t * 8) * 64 + kt) * 512;
        fragstride = 64 * 512;
    } else {
        int lb = bid - 512;
        int t = lb >> 6, rem = lb & 63;
        int kf = rem >> 4, cch = rem & 15;
        src = Wu + ((size_t)t * HIDN + kf * 32) * SZ + cch * 128;
        rowstride = SZ;
        dst = WuP + ((size_t)(t * 128 + cch * 8) * 4 + kf) * 512;
        fragstride = 4 * 512;
    }
#pragma unroll
    for (int i = 0; i < 4; i++) {
        int row = (tid >> 5) + 8 * i, quad = tid & 31;
        f32x4 v = *(const f32x4*)(src + (size_t)row * rowstride + quad * 4);
        tile[row][quad * 4 + 0] = v.x; tile[row][quad * 4 + 1] = v.y;
        tile[row][quad * 4 + 2] = v.z; tile[row][quad * 4 + 3] = v.w;
    }
    __syncthreads();
    int w = tid >> 6, lane = tid & 63, lr = lane & 15, lq = lane >> 4;
#pragma unroll
    for (int ii = 0; ii < 2; ii++) {
        int hf = w * 2 + ii;
        bf16x8 o;
#pragma unroll
        for (int j = 0; j < 8; j++) {
            int kloc = (j < 4) ? (4 * lq + j) : (16 + 4 * lq + j - 4);
            o[j] = f2b(tile[kloc][hf * 16 + lr]);
        }
        *(bf16x8*)(dst + (size_t)hf * fragstride + lane * 8) = o;
    }
}

// ---- GEMM1 (split-K=4): H[base+r][h] += x[g(r)][kchunk] . Wd[t][k][h] ----
// bid encoding: t = bid&7 (XCD pinning), ks = (bid>>3)&3, tile = bid>>5
__global__ __launch_bounds__(256) void k_gemm1(const float* __restrict__ x,
                                               const bf16_t* __restrict__ WdP,
                                               const int* __restrict__ idxb,
                                               const int* __restrict__ meta,
                                               float* __restrict__ H) {
    int bid = blockIdx.x;
    int t = bid & 7, ks = (bid >> 3) & 3, tile = bid >> 5;
    int n = meta[t];
    int r0 = tile * 32;
    if (r0 >= n) return;
    int base = meta[16 + t];
    int tid = threadIdx.x, lane = tid & 63, w = tid >> 6;
    int rg = w & 1, cg = w >> 1, lr = lane & 15, lq = lane >> 4;

    int br = r0 + rg * 16 + lr;
    int g = idxb[base + (br < n ? br : n - 1)];
    const float* xrow = x + (size_t)g * SZ + ks * KCH + 4 * lq;
    const bf16_t* wb = WdP + ((size_t)(t * 8 + cg * 4) * 64 + ks * 16) * 512 + lane * 8;

    f32x4 acc[4] = {};
#pragma unroll 4
    for (int kfi = 0; kfi < 16; kfi++) {
        f32x4 lo = *(const f32x4*)(xrow + kfi * 32);
        f32x4 hi = *(const f32x4*)(xrow + kfi * 32 + 16);
        bf16x8 a;
        a[0] = f2b(lo.x); a[1] = f2b(lo.y); a[2] = f2b(lo.z); a[3] = f2b(lo.w);
        a[4] = f2b(hi.x); a[5] = f2b(hi.y); a[6] = f2b(hi.z); a[7] = f2b(hi.w);
#pragma unroll
        for (int hf = 0; hf < 4; hf++) {
            bf16x8 b = *(const bf16x8*)(wb + (size_t)(hf * 64 + kfi) * 512);
            acc[hf] = __builtin_amdgcn_mfma_f32_16x16x32_bf16(a, b, acc[hf], 0, 0, 0);
        }
    }
#pragma unroll
    for (int hf = 0; hf < 4; hf++) {
        int h = cg * 64 + hf * 16 + lr;
#pragma unroll
        for (int reg = 0; reg < 4; reg++) {
            int r = r0 + rg * 16 + 4 * lq + reg;
            if (r < n) atomicAdd(&H[(size_t)(base + r) * HIDN + h], acc[hf][reg]);
        }
    }
}

// ---- bias + silu + pack Hb into A-fragment layout ----
__global__ __launch_bounds__(256) void k_silu(const float* __restrict__ bd,
                                              const int* __restrict__ rowtask,
                                              const float* __restrict__ H,
                                              bf16_t* __restrict__ HbP) {
    int rt = blockIdx.x;
    int w = threadIdx.x >> 6, lane = threadIdx.x & 63;
    int kf = w, lr = lane & 15, lq = lane >> 4;
    int R = rt * 16 + lr;
    int t = rowtask[R];
    t = t < 0 ? 0 : (t > 7 ? 7 : t);
    const float* hp = H + (size_t)R * HIDN + kf * 32 + 4 * lq;
    f32x4 lo = *(const f32x4*)hp;
    f32x4 hi = *(const f32x4*)(hp + 16);
    const float* bp = bd + t * HIDN + kf * 32 + 4 * lq;
    f32x4 blo = *(const f32x4*)bp;
    f32x4 bhi = *(const f32x4*)(bp + 16);
    float v[8] = {lo.x + blo.x, lo.y + blo.y, lo.z + blo.z, lo.w + blo.w,
                  hi.x + bhi.x, hi.y + bhi.y, hi.z + bhi.z, hi.w + bhi.w};
    bf16x8 o;
#pragma unroll
    for (int j = 0; j < 8; j++) o[j] = f2b(v[j] / (1.f + __expf(-v[j])));
    *(bf16x8*)(HbP + ((size_t)(rt * 4 + kf) * 64 + lane) * 8) = o;
}

// ---- GEMM2 + residual + passthrough tail ----
// bid<8192: t = bid&7 (XCD pinning), tile = (bid>>3)&127, cchunk = bid>>10
// bid>=8192: passthrough (bucket 8): copy 32 rows x 256 cols
__global__ __launch_bounds__(256) void k_gemm2(const float* __restrict__ x,
                                               const bf16_t* __restrict__ WuP,
                                               const float* __restrict__ bu,
                                               const bf16_t* __restrict__ HbP,
                                               const int* __restrict__ idxb,
                                               const int* __restrict__ meta,
                                               float* __restrict__ out) {
    int bid = blockIdx.x;
    int tid = threadIdx.x;
    if (bid >= 8192) {
        int pb = bid - 8192;
        int n8 = meta[8];
        int tile = pb & 127, half = pb >> 7;
        int r0 = tile * 32;
        if (r0 >= n8) return;
        int base8 = meta[16 + 8];
        int row = tid >> 3, cq = tid & 7;
        int r = r0 + row;
        if (r < n8) {
            int g = idxb[base8 + r];
            const f32x4* xs = (const f32x4*)(x + (size_t)g * SZ + half * 256) + cq;
            f32x4* os = (f32x4*)(out + (size_t)g * SZ + half * 256) + cq;
#pragma unroll
            for (int j = 0; j < 8; j++) __builtin_nontemporal_store(xs[j * 8], &os[j * 8]);
        }
        return;
    }
    int t = bid & 7, tile = (bid >> 3) & 127, cchunk = bid >> 10;
    int n = meta[t];
    int r0 = tile * 32;
    if (r0 >= n) return;
    int base = meta[16 + t];
    int lane = tid & 63, w = tid >> 6;
    int wr = w & 1, wc = w >> 1, lr = lane & 15, lq = lane >> 4;

    int rt = (base + r0) / 16 + wr;           // base is 32-aligned
    const bf16_t* ap = HbP + (size_t)rt * 4 * 512 + lane * 8;
    bf16x8 a[4];
#pragma unroll
    for (int kf = 0; kf < 4; kf++) a[kf] = *(const bf16x8*)(ap + kf * 512);

    const bf16_t* bp = WuP + ((size_t)(t * 128 + cchunk * 16 + wc * 8) * 4) * 512 + lane * 8;
    f32x4 acc[8] = {};
#pragma unroll
    for (int cf = 0; cf < 8; cf++) {
#pragma unroll
        for (int kf = 0; kf < 4; kf++) {
            bf16x8 b = *(const bf16x8*)(bp + (size_t)(cf * 4 + kf) * 512);
            acc[cf] = __builtin_amdgcn_mfma_f32_16x16x32_bf16(a[kf], b, acc[cf], 0, 0, 0);
        }
    }

    int gr[4];
#pragma unroll
    for (int reg = 0; reg < 4; reg++) {
        int r = r0 + wr * 16 + 4 * lq + reg;
        gr[reg] = (r < n) ? idxb[base + r] : -1;
    }
#pragma unroll
    for (int cf = 0; cf < 8; cf++) {
        int c = cchunk * 256 + wc * 128 + cf * 16 + lr;
        float bb = bu[t * SZ + c];
#pragma unroll
        for (int reg = 0; reg < 4; reg++) {
            if (gr[reg] >= 0) {
                size_t o = (size_t)gr[reg] * SZ + c;
                __builtin_nontemporal_store(x[o] + acc[cf][reg] + bb, &out[o]);
            }
        }
    }
}

extern "C" void kernel_launch(void* const* d_in, const int* in_sizes, int n_in,
                              void* d_out, int out_size, void* d_ws, size_t ws_size,
                              hipStream_t stream) {
    const float* x  = (const float*)d_in[0];
    const float* Wd = (const float*)d_in[1];
    const float* bd = (const float*)d_in[2];
    const float* Wu = (const float*)d_in[3];
    const float* bu = (const float*)d_in[4];
    const int* task = (const int*)d_in[5];
    float* out = (float*)d_out;

    char* ws = (char*)d_ws;
    int* idxb    = (int*)ws;
    int* rowtask = (int*)(ws + 17664);
    int* meta    = (int*)(ws + 35328);
    float* H     = (float*)(ws + 35840);
    bf16_t* HbP  = (bf16_t*)(ws + 2280448);
    bf16_t* WdP  = (bf16_t*)(ws + 3402752);
    bf16_t* WuP  = (bf16_t*)(ws + 7597056);

    k_prep<<<1025, 256, 0, stream>>>(Wd, Wu, task, WdP, WuP, H, meta, idxb, rowtask);
    k_gemm1<<<8 * KS * 128, 256, 0, stream>>>(x, WdP, idxb, meta, H);
    k_silu<<<PADTILES, 256, 0, stream>>>(bd, rowtask, H, HbP);
    k_gemm2<<<8192 + 1024, 256, 0, stream>>>(x, WuP, bu, HbP, idxb, meta, out);
}